// Round 4
// baseline (429.224 us; speedup 1.0000x reference)
//
#include <hip/hip_runtime.h>
#include <hip/hip_cooperative_groups.h>
#include <math.h>

namespace cg = cooperative_groups;

// Problem constants (fixed by setup_inputs)
#define BB   256
#define DIN  2048
#define DD   512
#define CC   1000
#define NN   50000
#define MM   (NN + BB)     // 50256
#define FILTER_K 100
#define SLOT 512           // per-class capacity; max real count ~85 old + 256 new

#define SK1  16            // split-K for z = x@Wf      (klen 128)
#define SKP  4             // split-K for p/out = z@B^T (klen 128)

// ---------------- workspace layout (float elements) ----------------
#define Z_OFF     0                          // z:     [256][512]
#define CNT_OFF   (Z_OFF + BB*DD)            // cnt:   [1024] int
#define ENTS_OFF  (CNT_OFF + 1024)           // ent_s: [1000][512]
#define IDXS_OFF  (ENTS_OFF + CC*SLOT)       // idx_s: [1000][512] int
#define WN_OFF    (IDXS_OFF + CC*SLOT)       // wn:    [1000][512]
#define ZP_OFF    (WN_OFF + CC*DD)           // zpart: [16][256][512]
#define PP_OFF    (ZP_OFF + SK1*BB*DD)       // ppart: [4][256][1000]
#define OP_OFF    (PP_OFF + SKP*BB*CC)       // opart: [4][256][1000]
// total ~5.3M floats ~21 MB

// ======== shared phase: Cp[sz] = A @ B^T   A:[256][512]  B:[CC][512] =====
// 64x64 tile, 4x4 micro, BK=16, klen=128; bid -> (nt 16, mt 4, sz 4)
__device__ __forceinline__ void gemm_abt_dev(
    const float* __restrict__ A, const float* __restrict__ Bm,
    float* __restrict__ Cp, float* smem, int bid, int tid) {
  float* As = smem;             // [16][68] k-major
  float* Bs = smem + 16 * 68;   // [16][68] k-major
  const int nt = bid & 15, mt = (bid >> 4) & 3, sz = bid >> 6;
  const int m0 = mt * 64, n0 = nt * 64, k0 = sz * 128;
  const int ar = tid >> 2, ac = (tid & 3) * 4;   // rows 0..63, k 0..15 (x4)
  const int tm = (tid >> 4) * 4, tn = (tid & 15) * 4;
  float acc[4][4] = {};
  float4 av = *(const float4*)&A[(size_t)(m0 + ar) * DD + k0 + ac];
  float4 bv = make_float4(0.f, 0.f, 0.f, 0.f);
  if (n0 + ar < CC) bv = *(const float4*)&Bm[(size_t)(n0 + ar) * DD + k0 + ac];
  for (int kk = 0; kk < 128; kk += 16) {
    __syncthreads();
    As[(ac + 0) * 68 + ar] = av.x; As[(ac + 1) * 68 + ar] = av.y;
    As[(ac + 2) * 68 + ar] = av.z; As[(ac + 3) * 68 + ar] = av.w;
    Bs[(ac + 0) * 68 + ar] = bv.x; Bs[(ac + 1) * 68 + ar] = bv.y;
    Bs[(ac + 2) * 68 + ar] = bv.z; Bs[(ac + 3) * 68 + ar] = bv.w;
    __syncthreads();
    if (kk + 16 < 128) {   // prefetch next K-tile; overlaps with compute below
      av = *(const float4*)&A[(size_t)(m0 + ar) * DD + k0 + kk + 16 + ac];
      if (n0 + ar < CC)
        bv = *(const float4*)&Bm[(size_t)(n0 + ar) * DD + k0 + kk + 16 + ac];
    }
#pragma unroll
    for (int q = 0; q < 16; ++q) {
      float4 a = *(const float4*)&As[q * 68 + tm];
      float4 b = *(const float4*)&Bs[q * 68 + tn];
      float aa[4] = {a.x, a.y, a.z, a.w};
      float bb[4] = {b.x, b.y, b.z, b.w};
#pragma unroll
      for (int i = 0; i < 4; ++i)
#pragma unroll
        for (int j = 0; j < 4; ++j) acc[i][j] += aa[i] * bb[j];
    }
  }
  float* Cb = Cp + (size_t)sz * BB * CC;
#pragma unroll
  for (int i = 0; i < 4; ++i) {
    int n = n0 + tn;
    if (n + 3 < CC) {
      *(float4*)&Cb[(size_t)(m0 + tm + i) * CC + n] =
          make_float4(acc[i][0], acc[i][1], acc[i][2], acc[i][3]);
    } else {
#pragma unroll
      for (int j = 0; j < 4; ++j)
        if (n + j < CC) Cb[(size_t)(m0 + tm + i) * CC + n + j] = acc[i][j];
    }
  }
}

// ===================== the whole pipeline, one launch ====================
__global__ __launch_bounds__(256) void mega(
    const float* __restrict__ x, const float* __restrict__ Wf,
    const float* __restrict__ Wc, const float* __restrict__ bc,
    const float* __restrict__ supports_in, const float* __restrict__ ent_in,
    const int* __restrict__ labels_idx, float* __restrict__ out,
    float* __restrict__ ws) {
  cg::grid_group grid = cg::this_grid();
  __shared__ float smem[3264];   // 13 KB, reused by every phase
  const int tid = threadIdx.x, bid = blockIdx.x;
  const int lane = tid & 63, wid = tid >> 6;

  float* z     = ws + Z_OFF;
  int*   cnt   = (int*)(ws + CNT_OFF);
  float* ent_s = ws + ENTS_OFF;
  int*   idx_s = (int*)(ws + IDXS_OFF);
  float* wn    = ws + WN_OFF;
  float* zpart = ws + ZP_OFF;
  float* ppart = ws + PP_OFF;
  float* opart = ws + OP_OFF;

  if (bid == 0)
    for (int i = tid; i < 1024; i += 256) cnt[i] = 0;

  // ---- Phase A: zpart = x @ Wf (64x128 tile, split-K 16) ----
  {
    float* As = smem;             // [16][68]
    float* Bs = smem + 16 * 68;   // [16][132]
    const int bx = bid & 3, by = (bid >> 2) & 3, bz = bid >> 4;
    const int m0 = by * 64, n0 = bx * 128, k0 = bz * 128;
    const int ar = tid >> 2, ac = (tid & 3) * 4;
    const int br = tid >> 4, bcn = (tid & 15) * 8;
    const int tm = (tid >> 4) * 4, tn = (tid & 15) * 4;
    float acc[4][8] = {};
    float4 av  = *(const float4*)&x[(size_t)(m0 + ar) * DIN + k0 + ac];
    float4 bv0 = *(const float4*)&Wf[(size_t)(k0 + br) * DD + n0 + bcn];
    float4 bv1 = *(const float4*)&Wf[(size_t)(k0 + br) * DD + n0 + bcn + 4];
    for (int kk = 0; kk < 128; kk += 16) {
      __syncthreads();
      As[(ac + 0) * 68 + ar] = av.x; As[(ac + 1) * 68 + ar] = av.y;
      As[(ac + 2) * 68 + ar] = av.z; As[(ac + 3) * 68 + ar] = av.w;
      *(float4*)&Bs[br * 132 + bcn] = bv0;
      *(float4*)&Bs[br * 132 + bcn + 4] = bv1;
      __syncthreads();
      if (kk + 16 < 128) {   // prefetch
        av  = *(const float4*)&x[(size_t)(m0 + ar) * DIN + k0 + kk + 16 + ac];
        bv0 = *(const float4*)&Wf[(size_t)(k0 + kk + 16 + br) * DD + n0 + bcn];
        bv1 = *(const float4*)&Wf[(size_t)(k0 + kk + 16 + br) * DD + n0 + bcn + 4];
      }
#pragma unroll
      for (int q = 0; q < 16; ++q) {
        float4 a  = *(const float4*)&As[q * 68 + tm];
        float4 b0 = *(const float4*)&Bs[q * 132 + tn];
        float4 b1 = *(const float4*)&Bs[q * 132 + tn + 64];
        float aa[4] = {a.x, a.y, a.z, a.w};
        float bb[8] = {b0.x, b0.y, b0.z, b0.w, b1.x, b1.y, b1.z, b1.w};
#pragma unroll
        for (int i = 0; i < 4; ++i)
#pragma unroll
          for (int j = 0; j < 8; ++j) acc[i][j] += aa[i] * bb[j];
      }
    }
    float* Cb = zpart + (size_t)bz * BB * DD;
#pragma unroll
    for (int i = 0; i < 4; ++i) {
      *(float4*)&Cb[(size_t)(m0 + tm + i) * DD + n0 + tn] =
          make_float4(acc[i][0], acc[i][1], acc[i][2], acc[i][3]);
      *(float4*)&Cb[(size_t)(m0 + tm + i) * DD + n0 + 64 + tn] =
          make_float4(acc[i][4], acc[i][5], acc[i][6], acc[i][7]);
    }
  }
  grid.sync();

  // ---- Phase B: z = sum(zpart) ----
  {
    int i = bid * 256 + tid;
    if (i < BB * DD / 4) {
      const float4* p4 = (const float4*)zpart;
      float4 a = p4[i];
#pragma unroll
      for (int s = 1; s < SK1; ++s) {
        float4 b = p4[(size_t)s * (BB * DD / 4) + i];
        a.x += b.x; a.y += b.y; a.z += b.z; a.w += b.w;
      }
      ((float4*)z)[i] = a;
    }
  }
  grid.sync();

  // ---- Phase C: ppart = z @ Wc^T ----
  gemm_abt_dev(z, Wc, ppart, smem, bid, tid);
  grid.sync();

  // ---- Phase D: rowstats (argmax + entropy) + scatter ----
  {
    const int b = bid;
    float* smv = smem;            int* smi = (int*)(smem + 4);
    float* ssm = smem + 8;        float* tsm = smem + 12;
    float r[4];
    float mv = -INFINITY; int mi = 0x7fffffff;
#pragma unroll
    for (int i = 0; i < 4; ++i) {
      int c = tid + 256 * i;
      if (c < CC) {
        float v = bc[c];
#pragma unroll
        for (int s = 0; s < SKP; ++s)
          v += ppart[(size_t)s * BB * CC + (size_t)b * CC + c];
        r[i] = v;
      } else r[i] = -INFINITY;
      if (r[i] > mv) { mv = r[i]; mi = c; }   // ascending c keeps first max
    }
#pragma unroll
    for (int o = 32; o > 0; o >>= 1) {
      float ov = __shfl_down(mv, o, 64);
      int oi = __shfl_down(mi, o, 64);
      if (ov > mv || (ov == mv && oi < mi)) { mv = ov; mi = oi; }
    }
    if (lane == 0) { smv[wid] = mv; smi[wid] = mi; }
    __syncthreads();
    if (tid == 0) {
#pragma unroll
      for (int w = 1; w < 4; ++w)
        if (smv[w] > smv[0] || (smv[w] == smv[0] && smi[w] < smi[0])) {
          smv[0] = smv[w]; smi[0] = smi[w];
        }
    }
    __syncthreads();
    const float m = smv[0]; const int am = smi[0];
    float s = 0.f, t = 0.f;
#pragma unroll
    for (int i = 0; i < 4; ++i) {
      if (tid + 256 * i < CC) {
        float u = r[i] - m;
        float e = expf(u);
        s += e; t += u * e;
      }
    }
#pragma unroll
    for (int o = 32; o > 0; o >>= 1) {
      s += __shfl_down(s, o, 64);
      t += __shfl_down(t, o, 64);
    }
    if (lane == 0) { ssm[wid] = s; tsm[wid] = t; }
    __syncthreads();
    if (tid == 0) {   // scatter this block's NEW row (index NN+b)
      float S = ssm[0] + ssm[1] + ssm[2] + ssm[3];
      float T = tsm[0] + tsm[1] + tsm[2] + tsm[3];
      float ent = logf(S) - T / S;
      int pos = atomicAdd(&cnt[am], 1);
      if (pos < SLOT) {
        ent_s[(size_t)am * SLOT + pos] = ent;
        idx_s[(size_t)am * SLOT + pos] = NN + b;
      }
    }
    // scatter OLD rows: one element per thread, coalesced reads
    int g = bid * 256 + tid;
    if (g < NN) {
      int c = labels_idx[g]; float e = ent_in[g];
      int pos = atomicAdd(&cnt[c], 1);
      if (pos < SLOT) {
        ent_s[(size_t)c * SLOT + pos] = e;
        idx_s[(size_t)c * SLOT + pos] = g;
      }
    }
  }
  grid.sync();

  // ---- Phase E: per-class select-K + normalized row sum + column norm ----
  {
    int* sel   = (int*)smem;          // [512]
    float* se  = smem + 512;          // [512]   (sort scratch)
    int* si    = (int*)(smem + 1024); // [512]   (sort scratch)
    float* part = smem + 512;         // [4][512] (after sort is done)
    float* tot  = smem + 2560;        // [4]
    for (int c = bid; c < CC; c += 256) {
      __syncthreads();
      int n = cnt[c]; if (n > SLOT) n = SLOT;
      int seln;
      if (n <= FILTER_K) {
        seln = n;
        for (int i = tid; i < n; i += 256) sel[i] = idx_s[(size_t)c * SLOT + i];
      } else {
        for (int i = tid; i < SLOT; i += 256) {
          if (i < n) { se[i] = ent_s[(size_t)c * SLOT + i]; si[i] = idx_s[(size_t)c * SLOT + i]; }
          else       { se[i] = INFINITY;                     si[i] = 0x7fffffff; }
        }
        __syncthreads();
        for (int k = 2; k <= SLOT; k <<= 1)
          for (int j = k >> 1; j > 0; j >>= 1) {
            for (int i = tid; i < SLOT; i += 256) {
              int ixj = i ^ j;
              if (ixj > i) {
                bool up = ((i & k) == 0);
                float e1 = se[i], e2 = se[ixj];
                int i1 = si[i], i2 = si[ixj];
                bool gt = (e1 > e2) || (e1 == e2 && i1 > i2);
                if (gt == up) { se[i] = e2; se[ixj] = e1; si[i] = i2; si[ixj] = i1; }
              }
            }
            __syncthreads();
          }
        seln = FILTER_K;
        for (int i = tid; i < FILTER_K; i += 256) sel[i] = si[i];
      }
      __syncthreads();

      // wave-per-row streaming; lane owns dims [lane*8, lane*8+8)
      float4 a0 = make_float4(0.f, 0.f, 0.f, 0.f), a1 = a0;
      for (int j = wid; j < seln; j += 4) {
        int ridx = sel[j];
        const float4* p4 = (const float4*)((ridx < NN)
            ? supports_in + (size_t)ridx * DD
            : z + (size_t)(ridx - NN) * DD);
        float4 v0 = p4[lane * 2], v1 = p4[lane * 2 + 1];
        float s = v0.x * v0.x + v0.y * v0.y + v0.z * v0.z + v0.w * v0.w
                + v1.x * v1.x + v1.y * v1.y + v1.z * v1.z + v1.w * v1.w;
#pragma unroll
        for (int o = 1; o < 64; o <<= 1) s += __shfl_xor(s, o, 64);
        float sc = 1.0f / fmaxf(sqrtf(s), 1e-12f);
        a0.x += v0.x * sc; a0.y += v0.y * sc; a0.z += v0.z * sc; a0.w += v0.w * sc;
        a1.x += v1.x * sc; a1.y += v1.y * sc; a1.z += v1.z * sc; a1.w += v1.w * sc;
      }
      __syncthreads();   // sort scratch dead; reuse as cross-wave partials
      *(float4*)&part[wid * 512 + lane * 8] = a0;
      *(float4*)&part[wid * 512 + lane * 8 + 4] = a1;
      __syncthreads();
      const int d = tid * 2;
      float wx = part[d] + part[512 + d] + part[1024 + d] + part[1536 + d];
      float wy = part[d + 1] + part[512 + d + 1] + part[1024 + d + 1] + part[1536 + d + 1];
      float ss = wx * wx + wy * wy;
#pragma unroll
      for (int o = 1; o < 64; o <<= 1) ss += __shfl_xor(ss, o, 64);
      if (lane == 0) tot[wid] = ss;
      __syncthreads();
      float S = tot[0] + tot[1] + tot[2] + tot[3];
      float sc = 1.0f / fmaxf(sqrtf(S), 1e-12f);
      ((float2*)(wn + (size_t)c * DD))[tid] = make_float2(wx * sc, wy * sc);
    }
  }
  grid.sync();

  // ---- Phase F: opart = z @ wn^T ----
  gemm_abt_dev(z, wn, opart, smem, bid, tid);
  grid.sync();

  // ---- Phase G: out = sum(opart) ----
  {
    int i = bid * 256 + tid;
    if (i < BB * CC / 4) {
      const float4* p4 = (const float4*)opart;
      float4 a = p4[i];
#pragma unroll
      for (int s = 1; s < SKP; ++s) {
        float4 b = p4[(size_t)s * (BB * CC / 4) + i];
        a.x += b.x; a.y += b.y; a.z += b.z; a.w += b.w;
      }
      ((float4*)out)[i] = a;
    }
  }
}

// ============================ launcher ===================================
extern "C" void kernel_launch(void* const* d_in, const int* in_sizes, int n_in,
                              void* d_out, int out_size, void* d_ws, size_t ws_size,
                              hipStream_t stream) {
  (void)in_sizes; (void)n_in; (void)out_size; (void)ws_size;
  const float* x           = (const float*)d_in[0];
  const float* Wf          = (const float*)d_in[1];
  const float* Wc          = (const float*)d_in[2];
  const float* bc          = (const float*)d_in[3];
  const float* supports_in = (const float*)d_in[4];
  const float* ent_in      = (const float*)d_in[5];
  const int*   labels_idx  = (const int*)d_in[6];
  float* out = (float*)d_out;
  float* ws  = (float*)d_ws;

  void* args[] = {(void*)&x, (void*)&Wf, (void*)&Wc, (void*)&bc,
                  (void*)&supports_in, (void*)&ent_in, (void*)&labels_idx,
                  (void*)&out, (void*)&ws};
  hipLaunchCooperativeKernel((const void*)mega, dim3(256), dim3(256),
                             args, 0, stream);
}

// Round 5
// 225.909 us; speedup vs baseline: 1.9000x; 1.9000x over previous
//
#include <hip/hip_runtime.h>
#include <hip/hip_bf16.h>
#include <math.h>

// Problem constants (fixed by setup_inputs)
#define BB   256
#define DIN  2048
#define DD   512
#define CC   1000
#define NN   50000
#define MM   (NN + BB)     // 50256
#define FILTER_K 100
#define SLOT 512           // per-class capacity; max real ~90 old + <=256 new

#define SK1  32            // split-K for z = x@Wf      (klen 64)
#define SKP  8             // split-K for p/out = z@B^T (klen 64)

// ---------------- workspace layout (float elements) ----------------
#define Z_OFF     0                          // z:     [256][512]
#define CNT_OFF   (Z_OFF + BB*DD)            // cnt:   [1024] int
#define ENTS_OFF  (CNT_OFF + 1024)           // ent_s: [1000][512]
#define IDXS_OFF  (ENTS_OFF + CC*SLOT)       // idx_s: [1000][512] int
#define WN_OFF    (IDXS_OFF + CC*SLOT)       // wn:    [1000][512]
#define ZP_OFF    (WN_OFF + CC*DD)           // zpart: [32][256][512]
#define PP_OFF    (ZP_OFF + SK1*BB*DD)       // ppart: [8][256][1000]
#define OP_OFF    (PP_OFF + SKP*BB*CC)       // opart: [8][256][1000]
// total ~10.0M floats ~40 MB (< 400 MB ws)

// ===== K1: zpart[s] = x @ Wf (k-slice s)  A:[256][2048] B:[2048][512] ====
// 64x128 tile, 4x8 micro, BK=16, klen=64; grid (4, 4, 32) = 512 blocks.
__global__ __launch_bounds__(256, 2) void gemm_ab_part(
    const float* __restrict__ A, const float* __restrict__ B,
    float* __restrict__ Cp) {
  __shared__ float As[16][68];
  __shared__ float Bs[16][132];
  const int tid = threadIdx.x;
  const int m0 = blockIdx.y * 64;
  const int n0 = blockIdx.x * 128;
  const int k0 = blockIdx.z * 64;
  const int ar = tid >> 2, ac = (tid & 3) * 4;   // A: 64 rows x 16 k
  const int br = tid >> 4, bcn = (tid & 15) * 8; // B: 16 k x 128 n
  const int tm = (tid >> 4) * 4, tn = (tid & 15) * 4;
  float acc[4][8] = {};
  float4 av  = *(const float4*)&A[(size_t)(m0 + ar) * DIN + k0 + ac];
  float4 bv0 = *(const float4*)&B[(size_t)(k0 + br) * DD + n0 + bcn];
  float4 bv1 = *(const float4*)&B[(size_t)(k0 + br) * DD + n0 + bcn + 4];
  for (int kk = 0; kk < 64; kk += 16) {
    __syncthreads();
    As[ac + 0][ar] = av.x; As[ac + 1][ar] = av.y;
    As[ac + 2][ar] = av.z; As[ac + 3][ar] = av.w;
    *(float4*)&Bs[br][bcn] = bv0;
    *(float4*)&Bs[br][bcn + 4] = bv1;
    __syncthreads();
    if (kk + 16 < 64) {   // register prefetch of next K-tile
      av  = *(const float4*)&A[(size_t)(m0 + ar) * DIN + k0 + kk + 16 + ac];
      bv0 = *(const float4*)&B[(size_t)(k0 + kk + 16 + br) * DD + n0 + bcn];
      bv1 = *(const float4*)&B[(size_t)(k0 + kk + 16 + br) * DD + n0 + bcn + 4];
    }
#pragma unroll
    for (int q = 0; q < 16; ++q) {
      float4 a  = *(const float4*)&As[q][tm];
      float4 b0 = *(const float4*)&Bs[q][tn];
      float4 b1 = *(const float4*)&Bs[q][tn + 64];
      float aa[4] = {a.x, a.y, a.z, a.w};
      float bb[8] = {b0.x, b0.y, b0.z, b0.w, b1.x, b1.y, b1.z, b1.w};
#pragma unroll
      for (int i = 0; i < 4; ++i)
#pragma unroll
        for (int j = 0; j < 8; ++j) acc[i][j] += aa[i] * bb[j];
    }
  }
  float* Cb = Cp + (size_t)blockIdx.z * BB * DD;
#pragma unroll
  for (int i = 0; i < 4; ++i) {
    *(float4*)&Cb[(size_t)(m0 + tm + i) * DD + n0 + tn] =
        make_float4(acc[i][0], acc[i][1], acc[i][2], acc[i][3]);
    *(float4*)&Cb[(size_t)(m0 + tm + i) * DD + n0 + 64 + tn] =
        make_float4(acc[i][4], acc[i][5], acc[i][6], acc[i][7]);
  }
}

// ==== K2/K5: Cp[s] = A @ B^T  A:[256][512] B:[CC][512]; 64x64 tile, =====
// 4x4 micro, BK=16, klen=64; grid (16, 4, 8) = 512 blocks.
__global__ __launch_bounds__(256, 2) void gemm_abt_part(
    const float* __restrict__ A, const float* __restrict__ Bm,
    float* __restrict__ Cp) {
  __shared__ float As[16][68];
  __shared__ float Bs[16][68];
  const int tid = threadIdx.x;
  const int m0 = blockIdx.y * 64;
  const int n0 = blockIdx.x * 64;
  const int k0 = blockIdx.z * 64;
  const int ar = tid >> 2, ac = (tid & 3) * 4;   // 64 rows x 16 k
  const int tm = (tid >> 4) * 4, tn = (tid & 15) * 4;
  float acc[4][4] = {};
  float4 av = *(const float4*)&A[(size_t)(m0 + ar) * DD + k0 + ac];
  float4 bv = make_float4(0.f, 0.f, 0.f, 0.f);
  if (n0 + ar < CC) bv = *(const float4*)&Bm[(size_t)(n0 + ar) * DD + k0 + ac];
  for (int kk = 0; kk < 64; kk += 16) {
    __syncthreads();
    As[ac + 0][ar] = av.x; As[ac + 1][ar] = av.y;
    As[ac + 2][ar] = av.z; As[ac + 3][ar] = av.w;
    Bs[ac + 0][ar] = bv.x; Bs[ac + 1][ar] = bv.y;
    Bs[ac + 2][ar] = bv.z; Bs[ac + 3][ar] = bv.w;
    __syncthreads();
    if (kk + 16 < 64) {   // register prefetch
      av = *(const float4*)&A[(size_t)(m0 + ar) * DD + k0 + kk + 16 + ac];
      if (n0 + ar < CC)
        bv = *(const float4*)&Bm[(size_t)(n0 + ar) * DD + k0 + kk + 16 + ac];
    }
#pragma unroll
    for (int q = 0; q < 16; ++q) {
      float4 a = *(const float4*)&As[q][tm];
      float4 b = *(const float4*)&Bs[q][tn];
      float aa[4] = {a.x, a.y, a.z, a.w};
      float bb[4] = {b.x, b.y, b.z, b.w};
#pragma unroll
      for (int i = 0; i < 4; ++i)
#pragma unroll
        for (int j = 0; j < 4; ++j) acc[i][j] += aa[i] * bb[j];
    }
  }
  float* Cb = Cp + (size_t)blockIdx.z * BB * CC;
#pragma unroll
  for (int i = 0; i < 4; ++i) {
    int n = n0 + tn;
    if (n + 3 < CC) {
      *(float4*)&Cb[(size_t)(m0 + tm + i) * CC + n] =
          make_float4(acc[i][0], acc[i][1], acc[i][2], acc[i][3]);
    } else {
#pragma unroll
      for (int j = 0; j < 4; ++j)
        if (n + j < CC) Cb[(size_t)(m0 + tm + i) * CC + n + j] = acc[i][j];
    }
  }
}

// ============ elementwise reduction of S split-K partials ================
template <int S>
__global__ __launch_bounds__(256) void reduce_part(
    const float* __restrict__ part, float* __restrict__ out, int n4) {
  int i = blockIdx.x * 256 + threadIdx.x;
  if (i >= n4) return;
  const float4* p4 = (const float4*)part;
  float4 a = p4[i];
#pragma unroll
  for (int s = 1; s < S; ++s) {
    float4 b = p4[(size_t)s * n4 + i];
    a.x += b.x; a.y += b.y; a.z += b.z; a.w += b.w;
  }
  ((float4*)out)[i] = a;
}

// ========== old-row scatter into per-class slots (inputs only) ===========
__global__ void scatter_old(const int* __restrict__ labels_idx,
                            const float* __restrict__ ent_in,
                            int* __restrict__ cnt,
                            float* __restrict__ ent_s, int* __restrict__ idx_s) {
  int m = blockIdx.x * blockDim.x + threadIdx.x;
  if (m >= NN) return;
  int c = labels_idx[m];
  int pos = atomicAdd(&cnt[c], 1);
  if (pos < SLOT) {
    ent_s[(size_t)c * SLOT + pos] = ent_in[m];
    idx_s[(size_t)c * SLOT + pos] = m;
  }
}

// == per-row argmax + entropy over p-partials + bias; scatters NEW row ====
__global__ __launch_bounds__(256) void rowstats(
    const float* __restrict__ ppart, const float* __restrict__ bc,
    int* __restrict__ cnt, float* __restrict__ ent_s,
    int* __restrict__ idx_s) {
  const int b = blockIdx.x, tid = threadIdx.x;
  const int lane = tid & 63, wid = tid >> 6;
  float r[4];
  float mv = -INFINITY; int mi = 0x7fffffff;
#pragma unroll
  for (int i = 0; i < 4; ++i) {
    int c = tid + 256 * i;
    if (c < CC) {
      float v = bc[c];
#pragma unroll
      for (int s = 0; s < SKP; ++s)
        v += ppart[(size_t)s * BB * CC + (size_t)b * CC + c];
      r[i] = v;
    } else r[i] = -INFINITY;
    if (r[i] > mv) { mv = r[i]; mi = c; }   // ascending c keeps first max
  }
#pragma unroll
  for (int o = 32; o > 0; o >>= 1) {
    float ov = __shfl_down(mv, o, 64);
    int oi = __shfl_down(mi, o, 64);
    if (ov > mv || (ov == mv && oi < mi)) { mv = ov; mi = oi; }
  }
  __shared__ float smv[4]; __shared__ int smi[4];
  __shared__ float ssm[4], tsm[4];
  if (lane == 0) { smv[wid] = mv; smi[wid] = mi; }
  __syncthreads();
  if (tid == 0) {
#pragma unroll
    for (int w = 1; w < 4; ++w)
      if (smv[w] > smv[0] || (smv[w] == smv[0] && smi[w] < smi[0])) {
        smv[0] = smv[w]; smi[0] = smi[w];
      }
  }
  __syncthreads();
  const float m = smv[0]; const int am = smi[0];
  float s = 0.f, t = 0.f;
#pragma unroll
  for (int i = 0; i < 4; ++i) {
    if (tid + 256 * i < CC) {
      float u = r[i] - m;
      float e = expf(u);
      s += e; t += u * e;
    }
  }
#pragma unroll
  for (int o = 32; o > 0; o >>= 1) {
    s += __shfl_down(s, o, 64);
    t += __shfl_down(t, o, 64);
  }
  if (lane == 0) { ssm[wid] = s; tsm[wid] = t; }
  __syncthreads();
  if (tid == 0) {   // scatter this block's NEW row (original index NN+b)
    float S = ssm[0] + ssm[1] + ssm[2] + ssm[3];
    float T = tsm[0] + tsm[1] + tsm[2] + tsm[3];
    float ent = logf(S) - T / S;
    int pos = atomicAdd(&cnt[am], 1);
    if (pos < SLOT) {
      ent_s[(size_t)am * SLOT + pos] = ent;
      idx_s[(size_t)am * SLOT + pos] = NN + b;
    }
  }
}

// ====== per-class: select K lowest-entropy rows, sum normalized rows =====
// Wave-per-row-PAIR streaming (2 independent loads + 2 interleaved reduce
// chains per iteration halves exposed latency); no barriers in the loop.
__global__ __launch_bounds__(256) void class_weights(
    const float* __restrict__ supports_in, const float* __restrict__ z,
    const float* __restrict__ ent_s, const int* __restrict__ idx_s,
    const int* __restrict__ cnt, float* __restrict__ wn) {
  const int c = blockIdx.x, tid = threadIdx.x;
  const int lane = tid & 63, wid = tid >> 6;
  int n = cnt[c]; if (n > SLOT) n = SLOT;

  __shared__ int sel[SLOT];
  __shared__ float se[SLOT];
  __shared__ int si[SLOT];
  int seln;
  if (n <= FILTER_K) {
    seln = n;
    for (int i = tid; i < n; i += 256) sel[i] = idx_s[(size_t)c * SLOT + i];
  } else {
    for (int i = tid; i < SLOT; i += 256) {
      if (i < n) { se[i] = ent_s[(size_t)c * SLOT + i]; si[i] = idx_s[(size_t)c * SLOT + i]; }
      else       { se[i] = INFINITY;                     si[i] = 0x7fffffff; }
    }
    __syncthreads();
    for (int k = 2; k <= SLOT; k <<= 1)
      for (int j = k >> 1; j > 0; j >>= 1) {
        for (int i = tid; i < SLOT; i += 256) {
          int ixj = i ^ j;
          if (ixj > i) {
            bool up = ((i & k) == 0);
            float e1 = se[i], e2 = se[ixj];
            int i1 = si[i], i2 = si[ixj];
            bool gt = (e1 > e2) || (e1 == e2 && i1 > i2);
            if (gt == up) { se[i] = e2; se[ixj] = e1; si[i] = i2; si[ixj] = i1; }
          }
        }
        __syncthreads();
      }
    seln = FILTER_K;
    for (int i = tid; i < FILTER_K; i += 256) sel[i] = si[i];
  }
  __syncthreads();

  // lane owns dims [lane*8, lane*8+8)
  float4 a0 = make_float4(0.f, 0.f, 0.f, 0.f), a1 = a0;
  const int npair = seln >> 1;
  for (int t = wid; t < npair; t += 4) {
    int r0 = sel[2 * t], r1 = sel[2 * t + 1];
    const float4* p0 = (const float4*)((r0 < NN)
        ? supports_in + (size_t)r0 * DD : z + (size_t)(r0 - NN) * DD);
    const float4* p1 = (const float4*)((r1 < NN)
        ? supports_in + (size_t)r1 * DD : z + (size_t)(r1 - NN) * DD);
    float4 u0 = p0[lane * 2], u1 = p0[lane * 2 + 1];
    float4 w0 = p1[lane * 2], w1 = p1[lane * 2 + 1];
    float s0 = u0.x * u0.x + u0.y * u0.y + u0.z * u0.z + u0.w * u0.w
             + u1.x * u1.x + u1.y * u1.y + u1.z * u1.z + u1.w * u1.w;
    float s1 = w0.x * w0.x + w0.y * w0.y + w0.z * w0.z + w0.w * w0.w
             + w1.x * w1.x + w1.y * w1.y + w1.z * w1.z + w1.w * w1.w;
#pragma unroll
    for (int o = 1; o < 64; o <<= 1) {
      s0 += __shfl_xor(s0, o, 64);
      s1 += __shfl_xor(s1, o, 64);
    }
    float c0 = 1.0f / fmaxf(sqrtf(s0), 1e-12f);
    float c1 = 1.0f / fmaxf(sqrtf(s1), 1e-12f);
    a0.x += u0.x * c0 + w0.x * c1; a0.y += u0.y * c0 + w0.y * c1;
    a0.z += u0.z * c0 + w0.z * c1; a0.w += u0.w * c0 + w0.w * c1;
    a1.x += u1.x * c0 + w1.x * c1; a1.y += u1.y * c0 + w1.y * c1;
    a1.z += u1.z * c0 + w1.z * c1; a1.w += u1.w * c0 + w1.w * c1;
  }
  if ((seln & 1) && wid == (npair & 3)) {   // odd tail row
    int r0 = sel[seln - 1];
    const float4* p0 = (const float4*)((r0 < NN)
        ? supports_in + (size_t)r0 * DD : z + (size_t)(r0 - NN) * DD);
    float4 u0 = p0[lane * 2], u1 = p0[lane * 2 + 1];
    float s0 = u0.x * u0.x + u0.y * u0.y + u0.z * u0.z + u0.w * u0.w
             + u1.x * u1.x + u1.y * u1.y + u1.z * u1.z + u1.w * u1.w;
#pragma unroll
    for (int o = 1; o < 64; o <<= 1) s0 += __shfl_xor(s0, o, 64);
    float c0 = 1.0f / fmaxf(sqrtf(s0), 1e-12f);
    a0.x += u0.x * c0; a0.y += u0.y * c0; a0.z += u0.z * c0; a0.w += u0.w * c0;
    a1.x += u1.x * c0; a1.y += u1.y * c0; a1.z += u1.z * c0; a1.w += u1.w * c0;
  }

  __shared__ float part[4][DD];
  *(float4*)&part[wid][lane * 8] = a0;
  *(float4*)&part[wid][lane * 8 + 4] = a1;
  __syncthreads();
  const int d = tid * 2;
  float wx = part[0][d] + part[1][d] + part[2][d] + part[3][d];
  float wy = part[0][d + 1] + part[1][d + 1] + part[2][d + 1] + part[3][d + 1];
  float ss = wx * wx + wy * wy;
#pragma unroll
  for (int o = 1; o < 64; o <<= 1) ss += __shfl_xor(ss, o, 64);
  __shared__ float tot[4];
  if (lane == 0) tot[wid] = ss;
  __syncthreads();
  float S = tot[0] + tot[1] + tot[2] + tot[3];
  float sc = 1.0f / fmaxf(sqrtf(S), 1e-12f);
  ((float2*)(wn + (size_t)c * DD))[tid] = make_float2(wx * sc, wy * sc);
}

// ============================ launcher ===================================
extern "C" void kernel_launch(void* const* d_in, const int* in_sizes, int n_in,
                              void* d_out, int out_size, void* d_ws, size_t ws_size,
                              hipStream_t stream) {
  (void)in_sizes; (void)n_in; (void)out_size; (void)ws_size;
  const float* x           = (const float*)d_in[0];
  const float* Wf          = (const float*)d_in[1];
  const float* Wc          = (const float*)d_in[2];
  const float* bc          = (const float*)d_in[3];
  const float* supports_in = (const float*)d_in[4];
  const float* ent_in      = (const float*)d_in[5];
  const int*   labels_idx  = (const int*)d_in[6];
  float* out = (float*)d_out;

  float* W = (float*)d_ws;
  float* z     = W + Z_OFF;
  int*   cnt   = (int*)(W + CNT_OFF);
  float* ent_s = W + ENTS_OFF;
  int*   idx_s = (int*)(W + IDXS_OFF);
  float* wn    = W + WN_OFF;
  float* zpart = W + ZP_OFF;
  float* ppart = W + PP_OFF;
  float* opart = W + OP_OFF;

  hipMemsetAsync(cnt, 0, 1024 * sizeof(int), stream);

  // old-row scatter (independent of the GEMM chain)
  scatter_old<<<(NN + 255) / 256, 256, 0, stream>>>(
      labels_idx, ent_in, cnt, ent_s, idx_s);

  // z = x @ Wf: 32-way split-K (512 blocks, 2/CU), then reduce
  gemm_ab_part<<<dim3(DD / 128, BB / 64, SK1), 256, 0, stream>>>(x, Wf, zpart);
  reduce_part<SK1><<<(BB * DD / 4 + 255) / 256, 256, 0, stream>>>(
      zpart, z, BB * DD / 4);

  // p partials = z @ Wc^T (512 blocks); bias+reduce+argmax+entropy+scatter
  gemm_abt_part<<<dim3((CC + 63) / 64, BB / 64, SKP), 256, 0, stream>>>(
      z, Wc, ppart);
  rowstats<<<BB, 256, 0, stream>>>(ppart, bc, cnt, ent_s, idx_s);

  // per-class selection + normalized accumulation + column norm
  class_weights<<<CC, 256, 0, stream>>>(supports_in, z, ent_s, idx_s, cnt, wn);

  // out partials = z @ wn^T, then reduce into d_out
  gemm_abt_part<<<dim3((CC + 63) / 64, BB / 64, SKP), 256, 0, stream>>>(
      z, wn, opart);
  reduce_part<SKP><<<(BB * CC / 4 + 255) / 256, 256, 0, stream>>>(
      opart, out, BB * CC / 4);
}